// Round 3
// baseline (701.134 us; speedup 1.0000x reference)
//
#include <hip/hip_runtime.h>

#define HDIM 16

// ---------------------------------------------------------------------------
// cnt[(dst<<shift)|(e&mask)] += 1  — per-node sub-buckets break atomic chains
// ---------------------------------------------------------------------------
__global__ void count_kernel(const int* __restrict__ dst, int* __restrict__ cnt,
                             int E, int shift, int mask) {
    int e = blockIdx.x * blockDim.x + threadIdx.x;
    if (e < E) atomicAdd(&cnt[(dst[e] << shift) | (e & mask)], 1);
}

// dinv[i] = rsqrt(1 + sum_b cnt[(i<<shift)+b])
__global__ void dinv_kernel(const int* __restrict__ cnt, float* __restrict__ dinv,
                            int n, int shift) {
    int i = blockIdx.x * blockDim.x + threadIdx.x;
    if (i < n) {
        int s = 0;
        for (int b = 0; b < (1 << shift); ++b) s += cnt[(i << shift) + b];
        dinv[i] = rsqrtf((float)s + 1.0f);
    }
}

// ---------------------------------------------------------------------------
// exclusive scan, in place; 256 threads x 16 elems = 4096 per block
// ---------------------------------------------------------------------------
__global__ void scan1_kernel(int* __restrict__ data, int* __restrict__ bsum, int n) {
    __shared__ int sh[256];
    int off = blockIdx.x * 4096 + threadIdx.x * 16;
    int vals[16];
    int local = 0;
#pragma unroll
    for (int k = 0; k < 16; ++k) {
        int v = (off + k < n) ? data[off + k] : 0;
        vals[k] = v;
        local += v;
    }
    sh[threadIdx.x] = local;
    __syncthreads();
#pragma unroll
    for (int d = 1; d < 256; d <<= 1) {
        int t = (threadIdx.x >= d) ? sh[threadIdx.x - d] : 0;
        __syncthreads();
        sh[threadIdx.x] += t;
        __syncthreads();
    }
    int run = (threadIdx.x == 0) ? 0 : sh[threadIdx.x - 1];
#pragma unroll
    for (int k = 0; k < 16; ++k) {
        if (off + k < n) data[off + k] = run;
        run += vals[k];
    }
    if (threadIdx.x == 0) bsum[blockIdx.x] = sh[255];
}

__global__ void scan2_kernel(int* __restrict__ bsum, int nb) {
    __shared__ int sh[512];
    int v = (threadIdx.x < nb) ? bsum[threadIdx.x] : 0;
    sh[threadIdx.x] = v;
    __syncthreads();
    for (int d = 1; d < 512; d <<= 1) {
        int t = (threadIdx.x >= d) ? sh[threadIdx.x - d] : 0;
        __syncthreads();
        sh[threadIdx.x] += t;
        __syncthreads();
    }
    int excl = (threadIdx.x == 0) ? 0 : sh[threadIdx.x - 1];
    if (threadIdx.x < nb) bsum[threadIdx.x] = excl;
}

__global__ void scan3_kernel(int* __restrict__ data, const int* __restrict__ bsum, int n) {
    int i = blockIdx.x * blockDim.x + threadIdx.x;
    if (i < n) data[i] += bsum[i >> 12];
}

// ---------------------------------------------------------------------------
// CSR fill: pos = rowptr[(d<<shift)|b]++ ; col[pos] = src
// ---------------------------------------------------------------------------
__global__ void fill_kernel(const int* __restrict__ src, const int* __restrict__ dst,
                            int* __restrict__ rowptr, int* __restrict__ col,
                            int E, int shift, int mask) {
    int e = blockIdx.x * blockDim.x + threadIdx.x;
    if (e < E) {
        int pos = atomicAdd(&rowptr[(dst[e] << shift) | (e & mask)], 1);
        col[pos] = src[e];
    }
}

// ---------------------------------------------------------------------------
// Y[n,16] = dinv[row] * (X[n,K] @ W[K,16])  — pre-scaled features
// ---------------------------------------------------------------------------
template <int K>
__global__ void gemm_kernel(const float* __restrict__ X, const float* __restrict__ W,
                            const float* __restrict__ dinv, float* __restrict__ Y, int n) {
    __shared__ float Wl[K * HDIM];
    for (int t = threadIdx.x; t < K * HDIM; t += blockDim.x) Wl[t] = W[t];
    __syncthreads();

    int row = blockIdx.x * blockDim.x + threadIdx.x;
    int stride = gridDim.x * blockDim.x;
    for (; row < n; row += stride) {
        float acc[HDIM];
#pragma unroll
        for (int j = 0; j < HDIM; ++j) acc[j] = 0.0f;
        const float* xr = X + (size_t)row * K;
#pragma unroll
        for (int k = 0; k < K; ++k) {
            float xv = xr[k];
#pragma unroll
            for (int j = 0; j < HDIM; ++j)
                acc[j] = fmaf(xv, Wl[k * HDIM + j], acc[j]);
        }
        float di = dinv[row];
        float4* yo = (float4*)(Y + (size_t)row * HDIM);
        yo[0] = make_float4(di * acc[0], di * acc[1], di * acc[2], di * acc[3]);
        yo[1] = make_float4(di * acc[4], di * acc[5], di * acc[6], di * acc[7]);
        yo[2] = make_float4(di * acc[8], di * acc[9], di * acc[10], di * acc[11]);
        yo[3] = make_float4(di * acc[12], di * acc[13], di * acc[14], di * acc[15]);
    }
}

// ---------------------------------------------------------------------------
// Gather over pre-scaled features hs[v,j] = dinv[v]*t[v,j]:
//   r_j = relu( dinv[i] * (sum_{s in N(i)} hs[s,j] + hs[i,j]) + bias_j )
//   FUSE_W2: out[i,:] = dinv[i] * (r @ W2)   (pre-scaled for layer 2)
//   else:    out[i,j] = r_j
// rowptr holds bucket ENDS after fill: start=(i==0)?0:rowptr[(i<<shift)-1],
// end = rowptr[((i+1)<<shift)-1]
// ---------------------------------------------------------------------------
template <bool FUSE_W2>
__global__ void gather_kernel(const int* __restrict__ col, const int* __restrict__ rowptr,
                              const float* __restrict__ hs, const float* __restrict__ dinv,
                              const float* __restrict__ bias, const float* __restrict__ W2,
                              float* __restrict__ out, int n, int shift) {
    __shared__ float W2l[HDIM * HDIM];
    if constexpr (FUSE_W2) {
        for (int t = threadIdx.x; t < HDIM * HDIM; t += blockDim.x) W2l[t] = W2[t];
        __syncthreads();
    }
    int idx = blockIdx.x * blockDim.x + threadIdx.x;
    if (idx >= n * HDIM) return;
    int i = idx >> 4;
    int j = idx & 15;
    int start = (i == 0) ? 0 : rowptr[(i << shift) - 1];
    int end = rowptr[((i + 1) << shift) - 1];
    float acc = 0.0f;
    for (int k = start; k < end; ++k) {
        int s = col[k];
        acc += hs[(size_t)s * HDIM + j];
    }
    float di = dinv[i];
    float r = fmaxf(fmaf(di, acc + hs[(size_t)i * HDIM + j], bias[j]), 0.0f);
    if constexpr (FUSE_W2) {
        float o = 0.0f;
#pragma unroll
        for (int jj = 0; jj < HDIM; ++jj) {
            float rv = __shfl(r, jj, HDIM);
            o = fmaf(rv, W2l[jj * HDIM + j], o);
        }
        out[idx] = di * o;
    } else {
        out[idx] = r;
    }
}

extern "C" void kernel_launch(void* const* d_in, const int* in_sizes, int n_in,
                              void* d_out, int out_size, void* d_ws, size_t ws_size,
                              hipStream_t stream) {
    const float* x  = (const float*)d_in[0];   // [n, 54]
    const int*   ei = (const int*)d_in[1];     // [2, E]
    const float* W1 = (const float*)d_in[2];   // [54, 16]
    const float* b1 = (const float*)d_in[3];   // [16]
    const float* W2 = (const float*)d_in[4];   // [16, 16]
    const float* b2 = (const float*)d_in[5];   // [16]
    float* out = (float*)d_out;

    const int E = in_sizes[1] / 2;             // 3,200,000
    const int n = in_sizes[0] / 54;            // 100,000
    const int* src = ei;
    const int* dst = ei + E;

    // pick bucket shift by workspace budget: 16, 4, or 1 buckets/node
    int shift = 4;
    {
        size_t fixed = (size_t)n * 4 + (size_t)n * HDIM * 8 + 2048 + (size_t)E * 4;
        while (shift > 0 && fixed + ((size_t)n << shift) * 4 > ws_size) shift -= 2;
    }
    const int mask = (1 << shift) - 1;
    const int M = n << shift;                  // total counters

    char* w = (char*)d_ws;
    float* dinv   = (float*)w;                 w += (size_t)n * 4;
    float* hA     = (float*)w;                 w += (size_t)n * HDIM * 4;
    float* hB     = (float*)w;                 w += (size_t)n * HDIM * 4;
    int*   rowptr = (int*)w;                   w += (size_t)M * 4;
    int*   bsum   = (int*)w;                   w += 512 * 4;
    int*   col    = (int*)w;                   // E ints

    const int B = 256;
    const int nb = (M + 4095) >> 12;           // scan blocks (<=512)

    // --- build degree + bucketed CSR (shared by both layers) ---
    hipMemsetAsync(rowptr, 0, (size_t)M * sizeof(int), stream);
    count_kernel<<<(E + B - 1) / B, B, 0, stream>>>(dst, rowptr, E, shift, mask);
    dinv_kernel<<<(n + B - 1) / B, B, 0, stream>>>(rowptr, dinv, n, shift);
    scan1_kernel<<<nb, 256, 0, stream>>>(rowptr, bsum, M);
    scan2_kernel<<<1, 512, 0, stream>>>(bsum, nb);
    scan3_kernel<<<(M + B - 1) / B, B, 0, stream>>>(rowptr, bsum, M);
    fill_kernel<<<(E + B - 1) / B, B, 0, stream>>>(src, dst, rowptr, col, E, shift, mask);

    // --- layer 1 transform (pre-scaled by dinv) ---
    gemm_kernel<54><<<1024, B, 0, stream>>>(x, W1, dinv, hA, n);

    // --- layer 1 aggregate + relu + fused @W2 (pre-scaled) -> hB ---
    gather_kernel<true><<<(n * HDIM + B - 1) / B, B, 0, stream>>>(
        col, rowptr, hA, dinv, b1, W2, hB, n, shift);

    // --- layer 2 aggregate + bias + relu -> out ---
    gather_kernel<false><<<(n * HDIM + B - 1) / B, B, 0, stream>>>(
        col, rowptr, hB, dinv, b2, nullptr, out, n, shift);
}